// Round 1
// baseline (3710.061 us; speedup 1.0000x reference)
//
#include <hip/hip_runtime.h>

typedef _Float16 h2 __attribute__((ext_vector_type(2)));

#define NB 128
#define NT 2048
#define NIN 32
#define NS 32
#define NM 8
#define NE 64
#define NH 128
#define NH3 384

__device__ __forceinline__ h2 mkh2(float a, float b) {
  h2 r; r[0] = (_Float16)a; r[1] = (_Float16)b; return r;
}

__device__ __forceinline__ float fdot2(h2 a, h2 b, float c) {
#if __has_builtin(__builtin_amdgcn_fdot2)
  return __builtin_amdgcn_fdot2(a, b, c, false);
#else
  return c + (float)a[0] * (float)b[0] + (float)a[1] * (float)b[1];
#endif
}

__device__ __forceinline__ float rcpf(float v) {
#if __has_builtin(__builtin_amdgcn_rcpf)
  return __builtin_amdgcn_rcpf(v);
#else
  return 1.0f / v;
#endif
}

__device__ __forceinline__ float sigmoid_f(float v) {
  return rcpf(1.0f + __expf(-v));
}

// tanh(x) = 1 - 2/(1 + e^{2x}); saturates correctly at +-inf via rcp(inf)=0
__device__ __forceinline__ float tanh_f(float v) {
  return 1.0f - 2.0f * rcpf(1.0f + __expf(2.0f * v));
}

__global__ __launch_bounds__(512, 2) void disc_rnn(
    const float* __restrict__ gx, const float* __restrict__ gy,
    const float* __restrict__ W_enc, const float* __restrict__ b_enc,
    const float* __restrict__ W_in, const float* __restrict__ W_rec,
    const float* __restrict__ b_s, const float* __restrict__ W_x,
    const float* __restrict__ W_h, const float* __restrict__ b_x,
    const float* __restrict__ b_h, const float* __restrict__ W_gate,
    const float* __restrict__ b_gate, float* __restrict__ out) {
  const int tid = threadIdx.x;
  const int b = blockIdx.x;

  __shared__ h2 x_h2[NIN / 2];    // current x_t, f16 packed
  __shared__ h2 h_h2[NH / 2];     // h state, f16 packed
  __shared__ h2 kst_h2[NS / 2];   // kstate, f16 packed
  __shared__ h2 inp_h2[33];       // [0..31]=encoded pairs, [32]={err, 0}
  __shared__ float ns_f[NM * NS]; // new_state (m*32+d)
  __shared__ float r_f[NH];
  __shared__ float n_f[NH];
  __shared__ float gpart[2][NM];
  __shared__ float y_buf[2];
  __shared__ float bg_lds[NM];

  // ---- init LDS state ----
  if (tid < NH / 2) h_h2[tid] = mkh2(0.f, 0.f);
  if (tid < NS / 2) kst_h2[tid] = mkh2(0.f, 0.f);
  if (tid < 33) inp_h2[tid] = mkh2(0.f, 0.f);
  if (tid >= 504) bg_lds[tid - 504] = b_gate[tid - 504];
  if (tid < NIN / 2) {
    const float* p = gx + ((size_t)b * NT) * NIN + 2 * tid;
    x_h2[tid] = mkh2(p[0], p[1]);
  }
  if (tid == 16) y_buf[0] = gy[(size_t)b * NT];

  // ---- per-thread register-resident weights ----
  h2 wreg[97];
  float bias0 = 0.f, bias1 = 0.f, bias2 = 0.f;
  float wg[NM];
#pragma unroll
  for (int m = 0; m < NM; ++m) wg[m] = 0.f;
  float h_reg = 0.f;

  if (tid < NH3) {
    const int j = tid;
#pragma unroll
    for (int k = 0; k < NH; k += 2)
      wreg[k >> 1] = mkh2(W_h[(size_t)k * NH3 + j], W_h[(size_t)(k + 1) * NH3 + j]);
#pragma unroll
    for (int e = 0; e < NE; e += 2)
      wreg[64 + (e >> 1)] = mkh2(W_x[(size_t)e * NH3 + j], W_x[(size_t)(e + 1) * NH3 + j]);
    wreg[96] = mkh2(W_x[(size_t)NE * NH3 + j], 0.f);
    bias0 = b_h[j];
    bias1 = b_x[j];
    if (tid < NH) {
#pragma unroll
      for (int m = 0; m < NM; ++m) wg[m] = W_gate[j * NM + m];
    }
  } else {
    const int u = tid - NH3;  // 0..127
    const int o0 = u, o1 = u + 128;
    const int m0 = o0 >> 5, d0 = o0 & 31;
    const int m1 = o1 >> 5, d1 = o1 & 31;
#pragma unroll
    for (int i = 0; i < NIN; i += 2) {
      wreg[16 + (i >> 1)] = mkh2(W_in[m0 * NIN * NS + i * NS + d0], W_in[m0 * NIN * NS + (i + 1) * NS + d0]);
      wreg[32 + (i >> 1)] = mkh2(W_in[m1 * NIN * NS + i * NS + d1], W_in[m1 * NIN * NS + (i + 1) * NS + d1]);
      wreg[48 + (i >> 1)] = mkh2(W_rec[m0 * NS * NS + i * NS + d0], W_rec[m0 * NS * NS + (i + 1) * NS + d0]);
      wreg[64 + (i >> 1)] = mkh2(W_rec[m1 * NS * NS + i * NS + d1], W_rec[m1 * NS * NS + (i + 1) * NS + d1]);
    }
    bias0 = b_s[o0];
    bias1 = b_s[o1];
    if (u < NE) {
#pragma unroll
      for (int i = 0; i < NIN; i += 2)
        wreg[i >> 1] = mkh2(W_enc[i * NE + u], W_enc[(i + 1) * NE + u]);
      bias2 = b_enc[u];
    }
  }
  __syncthreads();

  float z_reg = 0.f, xn_reg = 0.f, hn_reg = 0.f;

  for (int t = 0; t < NT; ++t) {
    // phase 0: prefetch next x/y into registers (latency hides under compute)
    float xp0 = 0.f, xp1 = 0.f, yp = 0.f;
    if (t + 1 < NT) {
      if (tid < NIN / 2) {
        const float* p = gx + ((size_t)b * NT + t + 1) * NIN + 2 * tid;
        xp0 = p[0];
        xp1 = p[1];
      }
      if (tid == 16) yp = gy[(size_t)b * NT + t + 1];
    }

    // phase 1: hz dots (H threads); encoded + new_state (S threads)
    float hpre = 0.f;
    if (tid < NH3) {
      float a = bias0, c = 0.f;
#pragma unroll
      for (int k = 0; k < NH / 4; ++k) {
        a = fdot2(h_h2[2 * k], wreg[2 * k], a);
        c = fdot2(h_h2[2 * k + 1], wreg[2 * k + 1], c);
      }
      hpre = a + c;
    } else {
      const int u = tid - NH3;
      if (u < NE) {
        float a = bias2;
#pragma unroll
        for (int i = 0; i < NIN / 2; ++i) a = fdot2(x_h2[i], wreg[i], a);
        ((_Float16*)inp_h2)[u] = (_Float16)tanh_f(a);
      }
      float s0 = bias0, s1 = bias1;
#pragma unroll
      for (int i = 0; i < NIN / 2; ++i) {
        s0 = fdot2(x_h2[i], wreg[16 + i], s0);
        s1 = fdot2(x_h2[i], wreg[32 + i], s1);
      }
#pragma unroll
      for (int i = 0; i < NS / 2; ++i) {
        s0 = fdot2(kst_h2[i], wreg[48 + i], s0);
        s1 = fdot2(kst_h2[i], wreg[64 + i], s1);
      }
      ns_f[u] = tanh_f(s0);
      ns_f[u + 128] = tanh_f(s1);
    }
    __syncthreads();  // (1) encoded + new_state visible

    // phase 2: xz dots, z/r; write prefetched x
    if (tid < NH3) {
      float a = bias1, c = 0.f;
#pragma unroll
      for (int e = 0; e < 16; ++e) {
        a = fdot2(inp_h2[2 * e], wreg[64 + 2 * e], a);
        c = fdot2(inp_h2[2 * e + 1], wreg[64 + 2 * e + 1], c);
      }
      a = fdot2(inp_h2[32], wreg[96], a);
      const float xpre = a + c;
      if (tid < NH) {
        z_reg = sigmoid_f(xpre + hpre);
      } else if (tid < 2 * NH) {
        r_f[tid - NH] = sigmoid_f(xpre + hpre);
      } else {
        xn_reg = xpre;
        hn_reg = hpre;
      }
      if (t + 1 < NT) {
        if (tid < NIN / 2) x_h2[tid] = mkh2(xp0, xp1);
        if (tid == 16) y_buf[(t + 1) & 1] = yp;
      }
    }
    __syncthreads();  // (2) r visible

    // phase 3: n
    if (tid >= 2 * NH && tid < NH3) {
      const int i = tid - 2 * NH;
      n_f[i] = tanh_f(xn_reg + r_f[i] * hn_reg);
    }
    __syncthreads();  // (3) n visible

    // phase 4: h_new + gate logit partial reduce
    if (tid < NH) {
      const float hnew = (1.f - z_reg) * n_f[tid] + z_reg * h_reg;
      h_reg = hnew;
      ((_Float16*)h_h2)[tid] = (_Float16)hnew;
      float p[NM];
#pragma unroll
      for (int m = 0; m < NM; ++m) p[m] = hnew * wg[m];
#pragma unroll
      for (int off = 32; off >= 1; off >>= 1) {
#pragma unroll
        for (int m = 0; m < NM; ++m) p[m] += __shfl_xor(p[m], off, 64);
      }
      if ((tid & 63) == 0) {
#pragma unroll
        for (int m = 0; m < NM; ++m) gpart[tid >> 6][m] = p[m];
      }
    }
    __syncthreads();  // (4) gate partials visible

    // phase 5: softmax + kstate_new + pred/err
    if (tid < NS) {
      float gl[NM];
      float mx = -1e30f;
#pragma unroll
      for (int m = 0; m < NM; ++m) {
        gl[m] = gpart[0][m] + gpart[1][m] + bg_lds[m];
        mx = fmaxf(mx, gl[m]);
      }
      float s = 0.f;
#pragma unroll
      for (int m = 0; m < NM; ++m) {
        gl[m] = __expf(gl[m] - mx);
        s += gl[m];
      }
      const float rs = rcpf(s);
      float ks = 0.f;
#pragma unroll
      for (int m = 0; m < NM; ++m) ks += gl[m] * ns_f[m * NS + tid];
      ks *= rs;
      ((_Float16*)kst_h2)[tid] = (_Float16)ks;
      if (tid == NS - 1) {
        out[(size_t)b * NT + t] = ks;
        const float err = ks - y_buf[t & 1];
        ((_Float16*)inp_h2)[64] = (_Float16)err;
      }
    }
    __syncthreads();  // (5) end of step
  }
}

extern "C" void kernel_launch(void* const* d_in, const int* in_sizes, int n_in,
                              void* d_out, int out_size, void* d_ws, size_t ws_size,
                              hipStream_t stream) {
  const float* x = (const float*)d_in[0];
  const float* y = (const float*)d_in[1];
  const float* W_enc = (const float*)d_in[2];
  const float* b_enc = (const float*)d_in[3];
  const float* W_in = (const float*)d_in[4];
  const float* W_rec = (const float*)d_in[5];
  const float* b_s = (const float*)d_in[6];
  const float* W_x = (const float*)d_in[7];
  const float* W_h = (const float*)d_in[8];
  const float* b_x = (const float*)d_in[9];
  const float* b_h = (const float*)d_in[10];
  const float* W_gate = (const float*)d_in[11];
  const float* b_gate = (const float*)d_in[12];

  disc_rnn<<<dim3(NB), dim3(512), 0, stream>>>(
      x, y, W_enc, b_enc, W_in, W_rec, b_s, W_x, W_h, b_x, b_h, W_gate, b_gate,
      (float*)d_out);
}

// Round 2
// 2676.798 us; speedup vs baseline: 1.3860x; 1.3860x over previous
//
#include <hip/hip_runtime.h>

typedef _Float16 h2 __attribute__((ext_vector_type(2)));
typedef _Float16 h8 __attribute__((ext_vector_type(8)));

#define NB 128
#define NT 2048
#define NIN 32
#define NS 32
#define NM 8
#define NE 64
#define NH 128
#define NH3 384

__device__ __forceinline__ h2 mkh2(float a, float b) {
  h2 r; r[0] = (_Float16)a; r[1] = (_Float16)b; return r;
}

template <int I>
__device__ __forceinline__ h2 pick2(h8 v) {
  return __builtin_shufflevector(v, v, 2 * I, 2 * I + 1);
}

__device__ __forceinline__ float fdot2(h2 a, h2 b, float c) {
#if __has_builtin(__builtin_amdgcn_fdot2)
  return __builtin_amdgcn_fdot2(a, b, c, false);
#else
  return c + (float)a[0] * (float)b[0] + (float)a[1] * (float)b[1];
#endif
}

__device__ __forceinline__ float rcpf(float v) {
#if __has_builtin(__builtin_amdgcn_rcpf)
  return __builtin_amdgcn_rcpf(v);
#else
  return 1.0f / v;
#endif
}

__device__ __forceinline__ float sigmoid_f(float v) {
  return rcpf(1.0f + __expf(-v));
}

__device__ __forceinline__ float tanh_f(float v) {
  return 1.0f - 2.0f * rcpf(1.0f + __expf(2.0f * v));
}

// DPP sum-reduce toward lane 63 (row_shr 1,2,4,8 then row_bcast15/31).
template <int CTRL>
__device__ __forceinline__ float dppadd(float v) {
  int t = __builtin_amdgcn_update_dpp(0, __float_as_int(v), CTRL, 0xF, 0xF, true);
  return v + __int_as_float(t);
}
__device__ __forceinline__ float wave_reduce63(float v) {
  v = dppadd<0x111>(v);
  v = dppadd<0x112>(v);
  v = dppadd<0x114>(v);
  v = dppadd<0x118>(v);
  v = dppadd<0x142>(v);
  v = dppadd<0x143>(v);
  return v;  // lane 63 holds the 64-lane sum
}

// ---------------------------------------------------------------------------
// Precompute kernel: xpre[b, tc, j] = b_x[j] + tanh(x@W_enc + b_enc) @ W_x[:64, j]
// ---------------------------------------------------------------------------
#define TCH 32
__global__ __launch_bounds__(384, 2) void pre_kernel(
    const float* __restrict__ gx, const float* __restrict__ W_enc,
    const float* __restrict__ b_enc, const float* __restrict__ W_x,
    const float* __restrict__ b_x, _Float16* __restrict__ xpre,
    int t0, int CH) {
  const int j = threadIdx.x;
  __shared__ h2 xs[16];
  __shared__ __align__(16) _Float16 encs[64];

  h2 wx[32];
#pragma unroll
  for (int i = 0; i < 32; ++i)
    wx[i] = mkh2(W_x[(size_t)(2 * i) * NH3 + j], W_x[(size_t)(2 * i + 1) * NH3 + j]);
  const float bx = b_x[j];
  h2 we[16];
  float be = 0.f;
  if (j < NE) {
#pragma unroll
    for (int i = 0; i < 16; ++i)
      we[i] = mkh2(W_enc[(2 * i) * NE + j], W_enc[(2 * i + 1) * NE + j]);
    be = b_enc[j];
  }

  for (int r = 0; r < TCH; ++r) {
    const int g = blockIdx.x * TCH + r;
    const int b = g / CH, tc = g % CH;
    const int t = t0 + tc;
    if (j < 16) {
      const float2 xx = ((const float2*)(gx + ((size_t)b * NT + t) * NIN))[j];
      xs[j] = mkh2(xx.x, xx.y);
    }
    __syncthreads();
    if (j < NE) {
      float a = be;
#pragma unroll
      for (int i = 0; i < 16; ++i) a = fdot2(xs[i], we[i], a);
      encs[j] = (_Float16)tanh_f(a);
    }
    __syncthreads();
    {
      const h8* ev8 = (const h8*)encs;
      float a = bx, c = 0.f;
#pragma unroll
      for (int i = 0; i < 8; ++i) {
        const h8 ev = ev8[i];
        a = fdot2(pick2<0>(ev), wx[4 * i + 0], a);
        c = fdot2(pick2<1>(ev), wx[4 * i + 1], c);
        a = fdot2(pick2<2>(ev), wx[4 * i + 2], a);
        c = fdot2(pick2<3>(ev), wx[4 * i + 3], c);
      }
      xpre[(size_t)g * NH3 + j] = (_Float16)(a + c);
    }
    __syncthreads();
  }
}

// ---------------------------------------------------------------------------
// Main recurrent kernel: 3 barriers/step, b128 LDS reads, DPP gate reduce.
// ---------------------------------------------------------------------------
__global__ __launch_bounds__(512, 2) void rnn_main(
    const float* __restrict__ gx, const float* __restrict__ gy,
    const _Float16* __restrict__ xpre,
    const float* __restrict__ W_h, const float* __restrict__ b_h,
    const float* __restrict__ W_in, const float* __restrict__ W_rec,
    const float* __restrict__ b_s, const float* __restrict__ W_x,
    const float* __restrict__ W_gate, const float* __restrict__ b_gate,
    float* __restrict__ out, float* __restrict__ state, int t0, int CH) {
  const int tid = threadIdx.x;
  const int b = blockIdx.x;

  __shared__ __align__(16) _Float16 h_sh[NH];
  __shared__ __align__(16) _Float16 kst_sh[NS];
  __shared__ __align__(16) _Float16 x_sh[NIN];
  __shared__ float ns_f[NM * NS];
  __shared__ float4 rxh[NH];   // .x=r, .y=xn, .z=hn
  __shared__ float2 gp2[8];    // per-wave gate partials (wave0: 0..3, wave1: 4..7)
  __shared__ float err_sh;

  h2 wreg[64];
  float g8[8];
#pragma unroll
  for (int m = 0; m < NM; ++m) g8[m] = 0.f;
  float bh = 0.f, wx64 = 0.f, bs1 = 0.f;
  float h_reg = 0.f;

  if (tid < NH3) {
    const int j = tid;
#pragma unroll
    for (int k = 0; k < 64; ++k)
      wreg[k] = mkh2(W_h[(size_t)(2 * k) * NH3 + j], W_h[(size_t)(2 * k + 1) * NH3 + j]);
    bh = b_h[j];
    wx64 = W_x[(size_t)NE * NH3 + j];
    if (tid < NH) {
#pragma unroll
      for (int m = 0; m < NM; ++m) g8[m] = W_gate[j * NM + m];
    }
  } else {
    const int u = tid - NH3;
    const int m0 = u >> 5, d0 = u & 31;
    const int m1 = 4 + (u >> 5), d1 = u & 31;
#pragma unroll
    for (int i = 0; i < 16; ++i) {
      wreg[i]      = mkh2(W_in[m0 * 1024 + (2 * i) * 32 + d0], W_in[m0 * 1024 + (2 * i + 1) * 32 + d0]);
      wreg[16 + i] = mkh2(W_in[m1 * 1024 + (2 * i) * 32 + d1], W_in[m1 * 1024 + (2 * i + 1) * 32 + d1]);
      wreg[32 + i] = mkh2(W_rec[m0 * 1024 + (2 * i) * 32 + d0], W_rec[m0 * 1024 + (2 * i + 1) * 32 + d0]);
      wreg[48 + i] = mkh2(W_rec[m1 * 1024 + (2 * i) * 32 + d1], W_rec[m1 * 1024 + (2 * i + 1) * 32 + d1]);
    }
    bh = b_s[u];
    bs1 = b_s[u + 128];
    if (u < 32) {
#pragma unroll
      for (int m = 0; m < NM; ++m) g8[m] = b_gate[m];
    }
  }

  float* st = state + b * (NH + NS + 1);
  if (t0 == 0) {
    if (tid < NH) h_sh[tid] = (_Float16)0.f;
    if (tid >= 384 && tid < 416) kst_sh[tid - 384] = (_Float16)0.f;
    if (tid == 415) err_sh = 0.f;
  } else {
    if (tid < NH) { h_reg = st[tid]; h_sh[tid] = (_Float16)h_reg; }
    if (tid >= 384 && tid < 416) kst_sh[tid - 384] = (_Float16)st[NH + (tid - 384)];
    if (tid == 415) err_sh = st[NH + NS];
  }

  // x staging pipeline (wave 7, lanes 0..15)
  float2 xw = make_float2(0.f, 0.f), xf = make_float2(0.f, 0.f);
  if (tid >= 448 && tid < 464) {
    const int li = tid - 448;
    const float2 x0 = ((const float2*)(gx + ((size_t)b * NT + t0) * NIN))[li];
    ((h2*)x_sh)[li] = mkh2(x0.x, x0.y);
    xw = ((const float2*)(gx + ((size_t)b * NT + t0 + 1) * NIN))[li];
    if (CH > 2) xf = ((const float2*)(gx + ((size_t)b * NT + t0 + 2) * NIN))[li];
  }
  // xpre pipeline (depth 2)
  _Float16 xp0 = (_Float16)0.f, xp1 = (_Float16)0.f, xp2 = (_Float16)0.f;
  if (tid < NH3) {
    xp0 = xpre[((size_t)b * CH + 0) * NH3 + tid];
    if (CH > 1) xp1 = xpre[((size_t)b * CH + 1) * NH3 + tid];
  }
  float yprev = 0.f;
  if (tid == 415) yprev = gy[(size_t)b * NT + t0];
  __syncthreads();

  float z_reg = 0.f, hpre = 0.f, xd0 = 0.f, xd1 = 0.f;

  for (int tc = 0; tc < CH; ++tc) {
    const int t = t0 + tc;
    // ---------------- P1: h-dots | x-dots | softmax tail of step t-1 --------
    if (tid < NH3) {
      xp2 = (tc + 2 < CH) ? xpre[((size_t)b * CH + tc + 2) * NH3 + tid] : (_Float16)0.f;
      float a0 = bh, a1 = 0.f, a2 = 0.f, a3 = 0.f;
      const h8* hv8 = (const h8*)h_sh;
#pragma unroll
      for (int i = 0; i < 16; ++i) {
        const h8 hv = hv8[i];
        a0 = fdot2(pick2<0>(hv), wreg[4 * i + 0], a0);
        a1 = fdot2(pick2<1>(hv), wreg[4 * i + 1], a1);
        a2 = fdot2(pick2<2>(hv), wreg[4 * i + 2], a2);
        a3 = fdot2(pick2<3>(hv), wreg[4 * i + 3], a3);
      }
      hpre = (a0 + a1) + (a2 + a3);
    } else {
      const int u = tid - NH3;
      if (u < 32 && tc > 0) {  // softmax -> kstate -> err for step t-1 (wave 6)
        float gl[8];
        float mx = -1e30f;
#pragma unroll
        for (int k = 0; k < 4; ++k) {
          const float2 p0 = gp2[k], p1 = gp2[4 + k];
          gl[2 * k] = p0.x + p1.x + g8[2 * k];
          gl[2 * k + 1] = p0.y + p1.y + g8[2 * k + 1];
        }
#pragma unroll
        for (int m = 0; m < 8; ++m) mx = fmaxf(mx, gl[m]);
        float s = 0.f;
#pragma unroll
        for (int m = 0; m < 8; ++m) { gl[m] = __expf(gl[m] - mx); s += gl[m]; }
        float ks = 0.f;
#pragma unroll
        for (int m = 0; m < 8; ++m) ks += gl[m] * ns_f[m * 32 + u];
        ks *= rcpf(s);
        kst_sh[u] = (_Float16)ks;
        if (u == 31) {
          out[(size_t)b * NT + (t - 1)] = ks;
          err_sh = ks - yprev;
          yprev = gy[(size_t)b * NT + t];
        }
      }
      // x-side of new_state (waves 6,7)
      const h8* xv8 = (const h8*)x_sh;
      float s0 = bh, s1 = bs1;
#pragma unroll
      for (int i = 0; i < 4; ++i) {
        const h8 xv = xv8[i];
        s0 = fdot2(pick2<0>(xv), wreg[4 * i + 0], s0);
        s1 = fdot2(pick2<0>(xv), wreg[16 + 4 * i + 0], s1);
        s0 = fdot2(pick2<1>(xv), wreg[4 * i + 1], s0);
        s1 = fdot2(pick2<1>(xv), wreg[16 + 4 * i + 1], s1);
        s0 = fdot2(pick2<2>(xv), wreg[4 * i + 2], s0);
        s1 = fdot2(pick2<2>(xv), wreg[16 + 4 * i + 2], s1);
        s0 = fdot2(pick2<3>(xv), wreg[4 * i + 3], s0);
        s1 = fdot2(pick2<3>(xv), wreg[16 + 4 * i + 3], s1);
      }
      xd0 = s0;
      xd1 = s1;
    }
    __syncthreads();
    // ---------------- P2: gate pre-activations | kstate-dots + new_state ----
    if (tid < NH3) {
      const float pre = (float)xp0 + err_sh * wx64;
      const float v = pre + hpre;
      if (tid < NH) {
        z_reg = sigmoid_f(v);
      } else if (tid < 2 * NH) {
        rxh[tid - NH].x = sigmoid_f(v);
      } else {
        rxh[tid - 2 * NH].y = pre;
        rxh[tid - 2 * NH].z = hpre;
      }
    } else {
      const h8* kv8 = (const h8*)kst_sh;
      float s0 = xd0, s1 = xd1;
#pragma unroll
      for (int i = 0; i < 4; ++i) {
        const h8 kv = kv8[i];
        s0 = fdot2(pick2<0>(kv), wreg[32 + 4 * i + 0], s0);
        s1 = fdot2(pick2<0>(kv), wreg[48 + 4 * i + 0], s1);
        s0 = fdot2(pick2<1>(kv), wreg[32 + 4 * i + 1], s0);
        s1 = fdot2(pick2<1>(kv), wreg[48 + 4 * i + 1], s1);
        s0 = fdot2(pick2<2>(kv), wreg[32 + 4 * i + 2], s0);
        s1 = fdot2(pick2<2>(kv), wreg[48 + 4 * i + 2], s1);
        s0 = fdot2(pick2<3>(kv), wreg[32 + 4 * i + 3], s0);
        s1 = fdot2(pick2<3>(kv), wreg[48 + 4 * i + 3], s1);
      }
      const int u = tid - NH3;
      ns_f[u] = tanh_f(s0);
      ns_f[u + 128] = tanh_f(s1);
      if (tid >= 448 && tid < 464 && tc + 1 < CH)
        ((h2*)x_sh)[tid - 448] = mkh2(xw.x, xw.y);
    }
    xp0 = xp1;
    xp1 = xp2;
    __syncthreads();
    // ---------------- P3: n, h_new, gate logits (waves 0,1) -----------------
    if (tid < NH) {
      const float4 rv = rxh[tid];
      const float n = tanh_f(rv.y + rv.x * rv.z);
      const float hnew = (1.f - z_reg) * n + z_reg * h_reg;
      h_reg = hnew;
      h_sh[tid] = (_Float16)hnew;
      float p[8];
#pragma unroll
      for (int m = 0; m < 8; ++m) p[m] = wave_reduce63(hnew * g8[m]);
      if ((tid & 63) == 63) {
        const int w = tid >> 6;
#pragma unroll
        for (int k = 0; k < 4; ++k) gp2[w * 4 + k] = make_float2(p[2 * k], p[2 * k + 1]);
      }
    } else if (tid >= 448 && tid < 464) {
      xw = xf;
      if (tc + 3 < CH)
        xf = ((const float2*)(gx + ((size_t)b * NT + t + 3) * NIN))[tid - 448];
    }
    __syncthreads();
  }

  // epilogue: softmax tail of the chunk's last step + state save
  if (tid >= NH3 && tid < NH3 + 32) {
    const int u = tid - NH3;
    float gl[8];
    float mx = -1e30f;
#pragma unroll
    for (int k = 0; k < 4; ++k) {
      const float2 p0 = gp2[k], p1 = gp2[4 + k];
      gl[2 * k] = p0.x + p1.x + g8[2 * k];
      gl[2 * k + 1] = p0.y + p1.y + g8[2 * k + 1];
    }
#pragma unroll
    for (int m = 0; m < 8; ++m) mx = fmaxf(mx, gl[m]);
    float s = 0.f;
#pragma unroll
    for (int m = 0; m < 8; ++m) { gl[m] = __expf(gl[m] - mx); s += gl[m]; }
    float ks = 0.f;
#pragma unroll
    for (int m = 0; m < 8; ++m) ks += gl[m] * ns_f[m * 32 + u];
    ks *= rcpf(s);
    st[NH + u] = ks;
    if (u == 31) {
      out[(size_t)b * NT + (t0 + CH - 1)] = ks;
      st[NH + NS] = ks - yprev;
    }
  }
  if (tid < NH) st[tid] = h_reg;
}

// ---------------------------------------------------------------------------
// Fallback (round-1 monolithic kernel) if workspace is too small.
// ---------------------------------------------------------------------------
__global__ __launch_bounds__(512, 2) void disc_rnn(
    const float* __restrict__ gx, const float* __restrict__ gy,
    const float* __restrict__ W_enc, const float* __restrict__ b_enc,
    const float* __restrict__ W_in, const float* __restrict__ W_rec,
    const float* __restrict__ b_s, const float* __restrict__ W_x,
    const float* __restrict__ W_h, const float* __restrict__ b_x,
    const float* __restrict__ b_h, const float* __restrict__ W_gate,
    const float* __restrict__ b_gate, float* __restrict__ out) {
  const int tid = threadIdx.x;
  const int b = blockIdx.x;

  __shared__ h2 x_h2[NIN / 2];
  __shared__ h2 h_h2[NH / 2];
  __shared__ h2 kst_h2[NS / 2];
  __shared__ h2 inp_h2[33];
  __shared__ float ns_f[NM * NS];
  __shared__ float r_f[NH];
  __shared__ float n_f[NH];
  __shared__ float gpart[2][NM];
  __shared__ float y_buf[2];
  __shared__ float bg_lds[NM];

  if (tid < NH / 2) h_h2[tid] = mkh2(0.f, 0.f);
  if (tid < NS / 2) kst_h2[tid] = mkh2(0.f, 0.f);
  if (tid < 33) inp_h2[tid] = mkh2(0.f, 0.f);
  if (tid >= 504) bg_lds[tid - 504] = b_gate[tid - 504];
  if (tid < NIN / 2) {
    const float* p = gx + ((size_t)b * NT) * NIN + 2 * tid;
    x_h2[tid] = mkh2(p[0], p[1]);
  }
  if (tid == 16) y_buf[0] = gy[(size_t)b * NT];

  h2 wreg[97];
  float bias0 = 0.f, bias1 = 0.f, bias2 = 0.f;
  float wg[NM];
#pragma unroll
  for (int m = 0; m < NM; ++m) wg[m] = 0.f;
  float h_reg = 0.f;

  if (tid < NH3) {
    const int j = tid;
#pragma unroll
    for (int k = 0; k < NH; k += 2)
      wreg[k >> 1] = mkh2(W_h[(size_t)k * NH3 + j], W_h[(size_t)(k + 1) * NH3 + j]);
#pragma unroll
    for (int e = 0; e < NE; e += 2)
      wreg[64 + (e >> 1)] = mkh2(W_x[(size_t)e * NH3 + j], W_x[(size_t)(e + 1) * NH3 + j]);
    wreg[96] = mkh2(W_x[(size_t)NE * NH3 + j], 0.f);
    bias0 = b_h[j];
    bias1 = b_x[j];
    if (tid < NH) {
#pragma unroll
      for (int m = 0; m < NM; ++m) wg[m] = W_gate[j * NM + m];
    }
  } else {
    const int u = tid - NH3;
    const int o0 = u, o1 = u + 128;
    const int m0 = o0 >> 5, d0 = o0 & 31;
    const int m1 = o1 >> 5, d1 = o1 & 31;
#pragma unroll
    for (int i = 0; i < NIN; i += 2) {
      wreg[16 + (i >> 1)] = mkh2(W_in[m0 * NIN * NS + i * NS + d0], W_in[m0 * NIN * NS + (i + 1) * NS + d0]);
      wreg[32 + (i >> 1)] = mkh2(W_in[m1 * NIN * NS + i * NS + d1], W_in[m1 * NIN * NS + (i + 1) * NS + d1]);
      wreg[48 + (i >> 1)] = mkh2(W_rec[m0 * NS * NS + i * NS + d0], W_rec[m0 * NS * NS + (i + 1) * NS + d0]);
      wreg[64 + (i >> 1)] = mkh2(W_rec[m1 * NS * NS + i * NS + d1], W_rec[m1 * NS * NS + (i + 1) * NS + d1]);
    }
    bias0 = b_s[o0];
    bias1 = b_s[o1];
    if (u < NE) {
#pragma unroll
      for (int i = 0; i < NIN; i += 2)
        wreg[i >> 1] = mkh2(W_enc[i * NE + u], W_enc[(i + 1) * NE + u]);
      bias2 = b_enc[u];
    }
  }
  __syncthreads();

  float z_reg = 0.f, xn_reg = 0.f, hn_reg = 0.f;

  for (int t = 0; t < NT; ++t) {
    float xp0 = 0.f, xp1 = 0.f, yp = 0.f;
    if (t + 1 < NT) {
      if (tid < NIN / 2) {
        const float* p = gx + ((size_t)b * NT + t + 1) * NIN + 2 * tid;
        xp0 = p[0];
        xp1 = p[1];
      }
      if (tid == 16) yp = gy[(size_t)b * NT + t + 1];
    }

    float hpre = 0.f;
    if (tid < NH3) {
      float a = bias0, c = 0.f;
#pragma unroll
      for (int k = 0; k < NH / 4; ++k) {
        a = fdot2(h_h2[2 * k], wreg[2 * k], a);
        c = fdot2(h_h2[2 * k + 1], wreg[2 * k + 1], c);
      }
      hpre = a + c;
    } else {
      const int u = tid - NH3;
      if (u < NE) {
        float a = bias2;
#pragma unroll
        for (int i = 0; i < NIN / 2; ++i) a = fdot2(x_h2[i], wreg[i], a);
        ((_Float16*)inp_h2)[u] = (_Float16)tanh_f(a);
      }
      float s0 = bias0, s1 = bias1;
#pragma unroll
      for (int i = 0; i < NIN / 2; ++i) {
        s0 = fdot2(x_h2[i], wreg[16 + i], s0);
        s1 = fdot2(x_h2[i], wreg[32 + i], s1);
      }
#pragma unroll
      for (int i = 0; i < NS / 2; ++i) {
        s0 = fdot2(kst_h2[i], wreg[48 + i], s0);
        s1 = fdot2(kst_h2[i], wreg[64 + i], s1);
      }
      ns_f[u] = tanh_f(s0);
      ns_f[u + 128] = tanh_f(s1);
    }
    __syncthreads();

    if (tid < NH3) {
      float a = bias1, c = 0.f;
#pragma unroll
      for (int e = 0; e < 16; ++e) {
        a = fdot2(inp_h2[2 * e], wreg[64 + 2 * e], a);
        c = fdot2(inp_h2[2 * e + 1], wreg[64 + 2 * e + 1], c);
      }
      a = fdot2(inp_h2[32], wreg[96], a);
      const float xpre = a + c;
      if (tid < NH) {
        z_reg = sigmoid_f(xpre + hpre);
      } else if (tid < 2 * NH) {
        r_f[tid - NH] = sigmoid_f(xpre + hpre);
      } else {
        xn_reg = xpre;
        hn_reg = hpre;
      }
      if (t + 1 < NT) {
        if (tid < NIN / 2) x_h2[tid] = mkh2(xp0, xp1);
        if (tid == 16) y_buf[(t + 1) & 1] = yp;
      }
    }
    __syncthreads();

    if (tid >= 2 * NH && tid < NH3) {
      const int i = tid - 2 * NH;
      n_f[i] = tanh_f(xn_reg + r_f[i] * hn_reg);
    }
    __syncthreads();

    if (tid < NH) {
      const float hnew = (1.f - z_reg) * n_f[tid] + z_reg * h_reg;
      h_reg = hnew;
      ((_Float16*)h_h2)[tid] = (_Float16)hnew;
      float p[NM];
#pragma unroll
      for (int m = 0; m < NM; ++m) p[m] = hnew * wg[m];
#pragma unroll
      for (int off = 32; off >= 1; off >>= 1) {
#pragma unroll
        for (int m = 0; m < NM; ++m) p[m] += __shfl_xor(p[m], off, 64);
      }
      if ((tid & 63) == 0) {
#pragma unroll
        for (int m = 0; m < NM; ++m) gpart[tid >> 6][m] = p[m];
      }
    }
    __syncthreads();

    if (tid < NS) {
      float gl[NM];
      float mx = -1e30f;
#pragma unroll
      for (int m = 0; m < NM; ++m) {
        gl[m] = gpart[0][m] + gpart[1][m] + bg_lds[m];
        mx = fmaxf(mx, gl[m]);
      }
      float s = 0.f;
#pragma unroll
      for (int m = 0; m < NM; ++m) {
        gl[m] = __expf(gl[m] - mx);
        s += gl[m];
      }
      const float rs = rcpf(s);
      float ks = 0.f;
#pragma unroll
      for (int m = 0; m < NM; ++m) ks += gl[m] * ns_f[m * NS + tid];
      ks *= rs;
      ((_Float16*)kst_h2)[tid] = (_Float16)ks;
      if (tid == NS - 1) {
        out[(size_t)b * NT + t] = ks;
        const float err = ks - y_buf[t & 1];
        ((_Float16*)inp_h2)[64] = (_Float16)err;
      }
    }
    __syncthreads();
  }
}

extern "C" void kernel_launch(void* const* d_in, const int* in_sizes, int n_in,
                              void* d_out, int out_size, void* d_ws, size_t ws_size,
                              hipStream_t stream) {
  const float* x = (const float*)d_in[0];
  const float* y = (const float*)d_in[1];
  const float* W_enc = (const float*)d_in[2];
  const float* b_enc = (const float*)d_in[3];
  const float* W_in = (const float*)d_in[4];
  const float* W_rec = (const float*)d_in[5];
  const float* b_s = (const float*)d_in[6];
  const float* W_x = (const float*)d_in[7];
  const float* W_h = (const float*)d_in[8];
  const float* b_x = (const float*)d_in[9];
  const float* b_h = (const float*)d_in[10];
  const float* W_gate = (const float*)d_in[11];
  const float* b_gate = (const float*)d_in[12];
  float* out = (float*)d_out;

  const size_t stateB = (size_t)NB * (NH + NS + 1) * sizeof(float);
  int CH = NT;
  while (CH > 64 && (size_t)NB * CH * NH3 * sizeof(_Float16) + stateB > ws_size)
    CH >>= 1;

  if ((size_t)NB * CH * NH3 * sizeof(_Float16) + stateB > ws_size) {
    // workspace too small: monolithic fallback
    disc_rnn<<<dim3(NB), dim3(512), 0, stream>>>(
        x, y, W_enc, b_enc, W_in, W_rec, b_s, W_x, W_h, b_x, b_h, W_gate, b_gate, out);
    return;
  }

  _Float16* xpre = (_Float16*)d_ws;
  float* state = (float*)((char*)d_ws + (size_t)NB * CH * NH3 * sizeof(_Float16));

  for (int t0 = 0; t0 < NT; t0 += CH) {
    pre_kernel<<<dim3(NB * CH / TCH), dim3(384), 0, stream>>>(
        x, W_enc, b_enc, W_x, b_x, xpre, t0, CH);
    rnn_main<<<dim3(NB), dim3(512), 0, stream>>>(
        x, y, xpre, W_h, b_h, W_in, W_rec, b_s, W_x, W_gate, b_gate,
        out, state, t0, CH);
  }
}